// Round 3
// baseline (179.501 us; speedup 1.0000x reference)
//
#include <hip/hip_runtime.h>
#include <hip/hip_bf16.h>
#include <stdint.h>
#include <stddef.h>

typedef __attribute__((ext_vector_type(8))) __bf16 bf16x8;
typedef __attribute__((ext_vector_type(4))) float f32x4;

#define DMODEL 1024
#define HEADS  16
#define DHEAD  64
#define BATCH  4
#define TSEQ   2048
#define MROWS  (BATCH * TSEQ)   // 8192
#define NE     (MROWS * DMODEL) // 8388608 (enc/dec elems)
#define NW     (DMODEL * DMODEL)

#define MiB (size_t)1048576
// workspace layout (peak ~87.1 MiB); kvp aliases encB (dead after K/V gemms)
#define QB_OFF   ((size_t)0)
#define KB_OFF   (16 * MiB)
#define VB_OFF   (32 * MiB)
#define ENC_OFF  (48 * MiB)
#define KVP_OFF  (48 * MiB)
#define DEC_OFF  (64 * MiB)
#define WQ_OFF   (80 * MiB)
#define WK_OFF   (82 * MiB)
#define WV_OFF   (84 * MiB)
#define KVT_OFF  (86 * MiB)
#define BQ_OFF   (87 * MiB)
#define BK_OFF   (87 * MiB + 4096)
#define BV_OFF   (87 * MiB + 8192)
#define G_OFF    (87 * MiB + 12288)
#define BT_OFF   (87 * MiB + 16384)
#define FLAG_OFF (87 * MiB + 20480)

// ---------------------------------------------------------------------------
// dtype detection. Little-endian f32: u16[2i] = LOW mantissa half (random bits
// -> 37.5% have bf16-exp-field >= 160); u16[2i+1] = sign/exp half (looks like
// valid bf16 -- round-2 bug was sampling THAT). True bf16 data: u16[2i] is
// element 2i, exp<160 always for sane data (exp>=160 => |x|>=2^33).
// ---------------------------------------------------------------------------
__global__ __launch_bounds__(256)
void detect_dtype(const void* __restrict__ enc, int* __restrict__ flag)
{
    __shared__ int cnt;
    if (threadIdx.x == 0) cnt = 0;
    __syncthreads();
    const unsigned short* u = (const unsigned short*)enc;
    int w = 0;
#pragma unroll
    for (int j = 0; j < 8; ++j) {
        const int k = threadIdx.x * 8 + j;          // 0..2047
        const unsigned short v = u[2 * k];          // LOW halves (even index)
        const int e = (v >> 7) & 0xFF;
        if (e >= 160) ++w;
    }
    atomicAdd(&cnt, w);
    __syncthreads();
    if (threadIdx.x == 0) *flag = (cnt > 128) ? 1 : 0;   // 1 => f32 buffers
}

// ---------------------------------------------------------------------------
// convert (or copy) an array to bf16, per runtime flag. n % 8 == 0.
// ---------------------------------------------------------------------------
__global__ __launch_bounds__(256)
void conv_to_bf16(const void* __restrict__ src, __bf16* __restrict__ dst,
                  int n, const int* __restrict__ flagp)
{
    const int f = *flagp;
    const int stride = gridDim.x * 256 * 8;
    for (int i = (blockIdx.x * 256 + threadIdx.x) * 8; i < n; i += stride) {
        bf16x8 o;
        if (f) {
            const float* s = (const float*)src;
            f32x4 a = *(const f32x4*)(s + i);
            f32x4 b = *(const f32x4*)(s + i + 4);
#pragma unroll
            for (int j = 0; j < 4; ++j) { o[j] = (__bf16)a[j]; o[j + 4] = (__bf16)b[j]; }
        } else {
            o = *(const bf16x8*)((const __bf16*)src + i);
        }
        *(bf16x8*)(dst + i) = o;
    }
}

// 5 small 1024-elem vectors in one launch (grid.x = array index)
__global__ __launch_bounds__(128)
void conv_small5(const void* s0, const void* s1, const void* s2, const void* s3,
                 const void* s4, __bf16* d0, __bf16* d1, __bf16* d2, __bf16* d3,
                 __bf16* d4, const int* __restrict__ flagp)
{
    const int f = *flagp;
    const void* s; __bf16* d;
    switch (blockIdx.x) {
        case 0: s = s0; d = d0; break;
        case 1: s = s1; d = d1; break;
        case 2: s = s2; d = d2; break;
        case 3: s = s3; d = d3; break;
        default: s = s4; d = d4; break;
    }
    const int i = threadIdx.x * 8;   // 128 thr * 8 = 1024
    bf16x8 o;
    if (f) {
        const float* sf = (const float*)s;
        f32x4 a = *(const f32x4*)(sf + i);
        f32x4 b = *(const f32x4*)(sf + i + 4);
#pragma unroll
        for (int j = 0; j < 4; ++j) { o[j] = (__bf16)a[j]; o[j + 4] = (__bf16)b[j]; }
    } else {
        o = *(const bf16x8*)((const __bf16*)s + i);
    }
    *(bf16x8*)(d + i) = o;
}

// ---------------------------------------------------------------------------
// GEMM: C[M,N] = A[M,K] @ W[N,K]^T + bias[N]   (bf16 in, f32 accum, bf16 out)
// m97 structure: 128x128 tile, BK=32, 4 waves (2x2), global_load_lds width=16.
// ---------------------------------------------------------------------------
__global__ __launch_bounds__(256)
void gemm_bt(const __bf16* __restrict__ A, const __bf16* __restrict__ W,
             const __bf16* __restrict__ bias, __bf16* __restrict__ C,
             int Mk, int Nk, int Kk)
{
    __shared__ __align__(16) __bf16 sA[2][128 * 32];
    __shared__ __align__(16) __bf16 sB[2][128 * 32];

    const int tid  = threadIdx.x;
    const int lane = tid & 63;
    const int wv   = tid >> 6;
    const int wm   = wv >> 1;
    const int wn   = wv & 1;
    const int bm   = blockIdx.y;
    const int bn   = blockIdx.x;

    const int l4 = lane & 15;
    const int g4 = lane >> 4;
    const int NT = Kk >> 5;

    const int s_row = lane >> 2;
    const int s_col = (lane & 3) * 8;

    auto stage = [&](int buf, int kt) {
        const int k0 = kt * 32 + s_col;
#pragma unroll
        for (int c2 = 0; c2 < 2; ++c2) {
            const int q = wv + c2 * 4;
            const int r = q * 16 + s_row;
            __builtin_amdgcn_global_load_lds(
                (const __attribute__((address_space(1))) void*)(A + (size_t)(bm * 128 + r) * Kk + k0),
                (__attribute__((address_space(3))) void*)(&sA[buf][q * 512]), 16, 0, 0);
            __builtin_amdgcn_global_load_lds(
                (const __attribute__((address_space(1))) void*)(W + (size_t)(bn * 128 + r) * Kk + k0),
                (__attribute__((address_space(3))) void*)(&sB[buf][q * 512]), 16, 0, 0);
        }
    };

    f32x4 acc[4][4] = {};

    stage(0, 0);
    __syncthreads();
    int buf = 0;
    for (int kt = 0; kt < NT; ++kt) {
        if (kt + 1 < NT) stage(buf ^ 1, kt + 1);

        bf16x8 af[4], bfr[4];
#pragma unroll
        for (int m = 0; m < 4; ++m)
            af[m] = *(const bf16x8*)&sA[buf][(wm * 64 + m * 16 + l4) * 32 + g4 * 8];
#pragma unroll
        for (int n = 0; n < 4; ++n)
            bfr[n] = *(const bf16x8*)&sB[buf][(wn * 64 + n * 16 + l4) * 32 + g4 * 8];

#pragma unroll
        for (int m = 0; m < 4; ++m)
#pragma unroll
            for (int n = 0; n < 4; ++n)
                acc[m][n] = __builtin_amdgcn_mfma_f32_16x16x32_bf16(af[m], bfr[n], acc[m][n], 0, 0, 0);

        __syncthreads();
        buf ^= 1;
    }

    const int crow0 = bm * 128 + wm * 64 + g4 * 4;
    const int ccol0 = bn * 128 + wn * 64 + l4;
#pragma unroll
    for (int n = 0; n < 4; ++n) {
        const int cc = ccol0 + n * 16;
        const float bv = (float)bias[cc];
#pragma unroll
        for (int m = 0; m < 4; ++m) {
            const int rr = crow0 + m * 16;
#pragma unroll
            for (int j = 0; j < 4; ++j)
                C[(size_t)(rr + j) * Nk + cc] = (__bf16)(acc[m][n][j] + bv);
        }
    }
}

// ---------------------------------------------------------------------------
// kv partials: kvp[c][b*16+h][d][e] = sum_{t in chunk c} K[b,t,h*64+d]*V[b,t,h*64+e]
// ---------------------------------------------------------------------------
__global__ __launch_bounds__(256)
void kv_partial(const __bf16* __restrict__ Kb, const __bf16* __restrict__ Vb,
                float* __restrict__ kvp)
{
    __shared__ __align__(16) float Ks[128][64];
    __shared__ __align__(16) float Vs[128][64];

    const int tid = threadIdx.x;
    const int bh  = blockIdx.x;
    const int c   = blockIdx.y;
    const int b   = bh >> 4, h = bh & 15;
    const size_t rowbase = (size_t)b * TSEQ + (size_t)c * 128;

#pragma unroll
    for (int i = 0; i < 4; ++i) {
        const int e = i * 2048 + tid * 8;
        const int t = e >> 6, d = e & 63;
        bf16x8 k8 = *(const bf16x8*)&Kb[(rowbase + t) * DMODEL + h * 64 + d];
        bf16x8 v8 = *(const bf16x8*)&Vb[(rowbase + t) * DMODEL + h * 64 + d];
#pragma unroll
        for (int j = 0; j < 8; ++j) {
            Ks[t][d + j] = (float)k8[j];
            Vs[t][d + j] = (float)v8[j];
        }
    }
    __syncthreads();

    const int d  = tid >> 2;
    const int e0 = (tid & 3) * 16;
    f32x4 acc[4] = {};
#pragma unroll 4
    for (int t = 0; t < 128; ++t) {
        const float kd = Ks[t][d];
        const f32x4* vr = (const f32x4*)&Vs[t][e0];
#pragma unroll
        for (int j = 0; j < 4; ++j) acc[j] += vr[j] * kd;
    }
    float* o = &kvp[(((size_t)c * 64 + bh) * 64 + d) * 64 + e0];
#pragma unroll
    for (int j = 0; j < 4; ++j) *((f32x4*)(o + j * 4)) = acc[j];
}

// ---------------------------------------------------------------------------
// reduce partials; kvT[bh][e][d] = scale * sum_c kvp  (e-major for att B-frag)
// ---------------------------------------------------------------------------
__global__ __launch_bounds__(256)
void kv_reduce(const float* __restrict__ kvp, __bf16* __restrict__ kvT)
{
    const int idx = blockIdx.x * 256 + threadIdx.x;
    const int bh  = idx >> 12;
    const int rem = idx & 4095;
    const int d = rem >> 6, e = rem & 63;
    float s = 0.f;
#pragma unroll
    for (int c = 0; c < 16; ++c) s += kvp[((size_t)c * 64 + bh) * 4096 + rem];
    kvT[(size_t)bh * 4096 + e * 64 + d] = (__bf16)(s * 0.125f);
}

// ---------------------------------------------------------------------------
// att + residual + LayerNorm, fused. 32 decoder rows/block, 128 thr (2 waves).
// Output dtype selected by runtime flag (f32 when inputs are f32).
// ---------------------------------------------------------------------------
__global__ __launch_bounds__(128)
void att_ln(const __bf16* __restrict__ Q, const __bf16* __restrict__ kvT,
            const __bf16* __restrict__ dec, const __bf16* __restrict__ gamma,
            const __bf16* __restrict__ beta, void* __restrict__ outv,
            const int* __restrict__ flagp)
{
    __shared__ __align__(16) __bf16 att_s[32][1032];

    const int f32o = *flagp;
    const int tid  = threadIdx.x;
    const int lane = tid & 63;
    const int wv   = tid >> 6;
    const int l4   = lane & 15, g4 = lane >> 4;
    const int t0   = blockIdx.x * 32;
    const int b    = t0 >> 11;

#pragma unroll
    for (int i = 0; i < 8; ++i) {
        const int h = wv * 8 + i;
        f32x4 acc[2][4] = {};
#pragma unroll
        for (int kk = 0; kk < 2; ++kk) {
            bf16x8 a0 = *(const bf16x8*)&Q[(size_t)(t0 + l4) * DMODEL + h * 64 + kk * 32 + g4 * 8];
            bf16x8 a1 = *(const bf16x8*)&Q[(size_t)(t0 + 16 + l4) * DMODEL + h * 64 + kk * 32 + g4 * 8];
#pragma unroll
            for (int n = 0; n < 4; ++n) {
                bf16x8 bfr = *(const bf16x8*)&kvT[(size_t)(b * 16 + h) * 4096 + (n * 16 + l4) * 64 + kk * 32 + g4 * 8];
                acc[0][n] = __builtin_amdgcn_mfma_f32_16x16x32_bf16(a0, bfr, acc[0][n], 0, 0, 0);
                acc[1][n] = __builtin_amdgcn_mfma_f32_16x16x32_bf16(a1, bfr, acc[1][n], 0, 0, 0);
            }
        }
#pragma unroll
        for (int m = 0; m < 2; ++m)
#pragma unroll
            for (int n = 0; n < 4; ++n)
#pragma unroll
                for (int j = 0; j < 4; ++j)
                    att_s[m * 16 + g4 * 4 + j][h * 64 + n * 16 + l4] = (__bf16)acc[m][n][j];
    }
    __syncthreads();

    const int r = tid >> 2, seg = tid & 3;
    const size_t grow = (size_t)t0 + r;
    float sum = 0.f, ss = 0.f;
#pragma unroll
    for (int i = 0; i < 32; ++i) {
        const int c0 = seg * 8 + i * 32;
        bf16x8 av = *(const bf16x8*)&att_s[r][c0];
        bf16x8 dv = *(const bf16x8*)&dec[grow * DMODEL + c0];
#pragma unroll
        for (int j = 0; j < 8; ++j) {
            const float x = (float)av[j] + (float)dv[j];
            sum += x; ss += x * x;
        }
    }
    sum += __shfl_xor(sum, 1); ss += __shfl_xor(ss, 1);
    sum += __shfl_xor(sum, 2); ss += __shfl_xor(ss, 2);
    const float mu   = sum * (1.f / 1024.f);
    const float var  = ss * (1.f / 1024.f) - mu * mu;
    const float rstd = rsqrtf(var + 1e-5f);

#pragma unroll
    for (int i = 0; i < 32; ++i) {
        const int c0 = seg * 8 + i * 32;
        bf16x8 av = *(const bf16x8*)&att_s[r][c0];
        bf16x8 dv = *(const bf16x8*)&dec[grow * DMODEL + c0];
        bf16x8 gv = *(const bf16x8*)&gamma[c0];
        bf16x8 bv = *(const bf16x8*)&beta[c0];
        float y[8];
#pragma unroll
        for (int j = 0; j < 8; ++j) {
            const float x = (float)av[j] + (float)dv[j];
            y[j] = (x - mu) * rstd * (float)gv[j] + (float)bv[j];
        }
        if (f32o) {
            float* o = (float*)outv + grow * DMODEL + c0;
            f32x4 y0, y1;
#pragma unroll
            for (int j = 0; j < 4; ++j) { y0[j] = y[j]; y1[j] = y[j + 4]; }
            *(f32x4*)(o)     = y0;
            *(f32x4*)(o + 4) = y1;
        } else {
            bf16x8 ov;
#pragma unroll
            for (int j = 0; j < 8; ++j) ov[j] = (__bf16)y[j];
            *(bf16x8*)((__bf16*)outv + grow * DMODEL + c0) = ov;
        }
    }
}

// ---------------------------------------------------------------------------
extern "C" void kernel_launch(void* const* d_in, const int* in_sizes, int n_in,
                              void* d_out, int out_size, void* d_ws, size_t ws_size,
                              hipStream_t stream)
{
    const void* enc   = d_in[0];
    const void* dec   = d_in[1];
    const void* Wq    = d_in[2];
    const void* bq    = d_in[3];
    const void* Wk    = d_in[4];
    const void* bk    = d_in[5];
    const void* Wv    = d_in[6];
    const void* bv    = d_in[7];
    const void* gamma = d_in[8];
    const void* beta  = d_in[9];

    char* ws = (char*)d_ws;
    __bf16* Qb   = (__bf16*)(ws + QB_OFF);
    __bf16* Kb   = (__bf16*)(ws + KB_OFF);
    __bf16* Vb   = (__bf16*)(ws + VB_OFF);
    __bf16* encB = (__bf16*)(ws + ENC_OFF);
    float*  kvp  = (float*) (ws + KVP_OFF);   // aliases encB (dead after K/V gemms)
    __bf16* decB = (__bf16*)(ws + DEC_OFF);
    __bf16* WqB  = (__bf16*)(ws + WQ_OFF);
    __bf16* WkB  = (__bf16*)(ws + WK_OFF);
    __bf16* WvB  = (__bf16*)(ws + WV_OFF);
    __bf16* kvT  = (__bf16*)(ws + KVT_OFF);
    __bf16* bqB  = (__bf16*)(ws + BQ_OFF);
    __bf16* bkB  = (__bf16*)(ws + BK_OFF);
    __bf16* bvB  = (__bf16*)(ws + BV_OFF);
    __bf16* gB   = (__bf16*)(ws + G_OFF);
    __bf16* btB  = (__bf16*)(ws + BT_OFF);
    int*    flag = (int*)   (ws + FLAG_OFF);

    detect_dtype<<<1, 256, 0, stream>>>(enc, flag);

    conv_to_bf16<<<4096, 256, 0, stream>>>(enc, encB, NE, flag);
    conv_to_bf16<<<4096, 256, 0, stream>>>(dec, decB, NE, flag);
    conv_to_bf16<<<512,  256, 0, stream>>>(Wq,  WqB,  NW, flag);
    conv_to_bf16<<<512,  256, 0, stream>>>(Wk,  WkB,  NW, flag);
    conv_to_bf16<<<512,  256, 0, stream>>>(Wv,  WvB,  NW, flag);
    conv_small5<<<5, 128, 0, stream>>>(bq, bk, bv, gamma, beta,
                                       bqB, bkB, bvB, gB, btB, flag);

    dim3 g(8, 64), blk(256);
    gemm_bt<<<g, blk, 0, stream>>>(decB, WqB, bqB, Qb, MROWS, DMODEL, DMODEL);
    gemm_bt<<<g, blk, 0, stream>>>(encB, WkB, bkB, Kb, MROWS, DMODEL, DMODEL);
    gemm_bt<<<g, blk, 0, stream>>>(encB, WvB, bvB, Vb, MROWS, DMODEL, DMODEL);
    kv_partial<<<dim3(64, 16), 256, 0, stream>>>(Kb, Vb, kvp);
    kv_reduce<<<1024, 256, 0, stream>>>(kvp, kvT);
    att_ln<<<256, 128, 0, stream>>>(Qb, kvT, decB, gB, btB, d_out, flag);
}

// Round 4
// 149.431 us; speedup vs baseline: 1.2012x; 1.2012x over previous
//
#include <hip/hip_runtime.h>
#include <hip/hip_bf16.h>
#include <stdint.h>
#include <stddef.h>

typedef __attribute__((ext_vector_type(8))) __bf16 bf16x8;
typedef __attribute__((ext_vector_type(4))) float f32x4;

#define DMODEL 1024
#define HEADS  16
#define BATCH  4
#define TSEQ   2048
#define MROWS  (BATCH * TSEQ)   // 8192

#define MiB (size_t)1048576
#define QB_OFF   ((size_t)0)          // 16 MiB bf16
#define KB_OFF   (16 * MiB)           // 16 MiB bf16
#define VB_OFF   (32 * MiB)           // 16 MiB bf16
#define KVP_OFF  (48 * MiB)           // 16 MiB f32 partials
#define WB_OFF   (64 * MiB)           // 6 MiB bf16 (Wq,Wk,Wv)
#define KVT_OFF  (70 * MiB)           // 512 KiB bf16

// ---------------------------------------------------------------------------
// convert the 3 weight matrices f32 -> bf16 (one launch, 18 MB traffic)
// ---------------------------------------------------------------------------
__global__ __launch_bounds__(256)
void conv_w(const float* __restrict__ Wq, const float* __restrict__ Wk,
            const float* __restrict__ Wv, __bf16* __restrict__ WB)
{
    const int bid = blockIdx.x;            // 0..1535
    const int sel = bid >> 9, blk = bid & 511;
    const float* src = (sel == 0) ? Wq : (sel == 1) ? Wk : Wv;
    const int i = blk * 2048 + threadIdx.x * 8;
    f32x4 a = *(const f32x4*)(src + i);
    f32x4 b = *(const f32x4*)(src + i + 4);
    bf16x8 o;
#pragma unroll
    for (int j = 0; j < 4; ++j) { o[j] = (__bf16)a[j]; o[j + 4] = (__bf16)b[j]; }
    *(bf16x8*)&WB[(size_t)sel * (DMODEL * DMODEL) + i] = o;
}

// ---------------------------------------------------------------------------
// Fused QKV GEMM: C = A[M,K](f32, inline-cvt) @ W[N,K]^T(bf16) + bias(f32)
// m97 structure: 128x128 tile, BK=32, 4 waves, dbuf LDS.
// A: reg-staged f32->bf16 (lane-linear ds_write_b128, conflict-free);
// B: global_load_lds width=16. sel = blockIdx.x>>3 chooses Q/K/V.
// ---------------------------------------------------------------------------
__global__ __launch_bounds__(256)
void qkv_gemm(const float* __restrict__ dec, const float* __restrict__ enc,
              const __bf16* __restrict__ WB,
              const float* __restrict__ bq, const float* __restrict__ bk,
              const float* __restrict__ bv,
              __bf16* __restrict__ Qb, __bf16* __restrict__ Kb,
              __bf16* __restrict__ Vb)
{
    __shared__ __align__(16) __bf16 sA[2][128 * 32];
    __shared__ __align__(16) __bf16 sB[2][128 * 32];

    const int tid  = threadIdx.x;
    const int lane = tid & 63;
    const int wv   = tid >> 6;
    const int wm   = wv >> 1;
    const int wn   = wv & 1;
    const int bx   = blockIdx.x;       // 0..23
    const int bm   = blockIdx.y;       // 0..63
    const int sel  = bx >> 3;          // 0=Q 1=K 2=V
    const int bn   = bx & 7;

    const float*  A    = (sel == 0) ? dec : enc;
    const __bf16* W    = WB + (size_t)sel * (DMODEL * DMODEL);
    const float*  bias = (sel == 0) ? bq : (sel == 1) ? bk : bv;
    __bf16*       C    = (sel == 0) ? Qb : (sel == 1) ? Kb : Vb;

    const int l4 = lane & 15;
    const int g4 = lane >> 4;
    const int NT = DMODEL / 32;        // 32 K-steps

    // staging maps (tile 128x32): bf16 idx = p*2048 + tid*8 -> row=idx>>5, k=idx&31
    const int r0 = tid >> 2;           // pass0 row (pass1: +64)
    const int k0 = (tid & 3) * 8;      // k within 32

    auto loadA = [&](int kt, f32x4 a[4]) {
#pragma unroll
        for (int p = 0; p < 2; ++p) {
            const float* src = A + (size_t)(bm * 128 + p * 64 + r0) * DMODEL + kt * 32 + k0;
            a[2 * p]     = *(const f32x4*)src;
            a[2 * p + 1] = *(const f32x4*)(src + 4);
        }
    };
    auto writeA = [&](int buf, f32x4 a[4]) {
#pragma unroll
        for (int p = 0; p < 2; ++p) {
            bf16x8 o;
#pragma unroll
            for (int j = 0; j < 4; ++j) {
                o[j]     = (__bf16)a[2 * p][j];
                o[j + 4] = (__bf16)a[2 * p + 1][j];
            }
            *(bf16x8*)&sA[buf][p * 2048 + tid * 8] = o;
        }
    };
    auto stageB = [&](int buf, int kt) {
#pragma unroll
        for (int p = 0; p < 2; ++p) {
            const int idx = p * 2048 + tid * 8;
            __builtin_amdgcn_global_load_lds(
                (const __attribute__((address_space(1))) void*)
                    (W + (size_t)(bn * 128 + p * 64 + r0) * DMODEL + kt * 32 + k0),
                (__attribute__((address_space(3))) void*)(&sB[buf][idx]), 16, 0, 0);
        }
    };

    f32x4 acc[4][4] = {};

    {
        f32x4 a0[4];
        loadA(0, a0);
        stageB(0, 0);
        writeA(0, a0);
    }
    __syncthreads();

    int buf = 0;
    for (int kt = 0; kt < NT; ++kt) {
        f32x4 an[4];
        const bool more = (kt + 1 < NT);
        if (more) { loadA(kt + 1, an); stageB(buf ^ 1, kt + 1); }

        bf16x8 af[4], bfr[4];
#pragma unroll
        for (int m = 0; m < 4; ++m)
            af[m] = *(const bf16x8*)&sA[buf][(wm * 64 + m * 16 + l4) * 32 + g4 * 8];
#pragma unroll
        for (int n = 0; n < 4; ++n)
            bfr[n] = *(const bf16x8*)&sB[buf][(wn * 64 + n * 16 + l4) * 32 + g4 * 8];

#pragma unroll
        for (int m = 0; m < 4; ++m)
#pragma unroll
            for (int n = 0; n < 4; ++n)
                acc[m][n] = __builtin_amdgcn_mfma_f32_16x16x32_bf16(af[m], bfr[n], acc[m][n], 0, 0, 0);

        if (more) writeA(buf ^ 1, an);
        __syncthreads();
        buf ^= 1;
    }

    // epilogue: C/D layout col = lane&15, row = (lane>>4)*4 + j
    const int crow0 = bm * 128 + wm * 64 + g4 * 4;
    const int ccol0 = bn * 128 + wn * 64 + l4;
#pragma unroll
    for (int n = 0; n < 4; ++n) {
        const int cc = ccol0 + n * 16;
        const float bv2 = bias[cc];
#pragma unroll
        for (int m = 0; m < 4; ++m) {
            const int rr = crow0 + m * 16;
#pragma unroll
            for (int j = 0; j < 4; ++j)
                C[(size_t)(rr + j) * DMODEL + cc] = (__bf16)(acc[m][n][j] + bv2);
        }
    }
}

// ---------------------------------------------------------------------------
// kv partials, register-tiled: block = (bh, chunk of 512 t), 4 waves.
// Wave w handles t-slice w*32..+32 of each 128-row substage; lane owns an
// 8x8 (d,e) tile -> 64 FMA per 32 B LDS read (compute-bound).
// kvp[c][bh][d][e], c = chunk*4 + wave (16 partials, summed by kv_reduce).
// ---------------------------------------------------------------------------
__global__ __launch_bounds__(256)
void kv_mm(const __bf16* __restrict__ Kb, const __bf16* __restrict__ Vb,
           float* __restrict__ kvp)
{
    __shared__ __align__(16) float Ks[128][64];
    __shared__ __align__(16) float Vs[128][64];

    const int tid = threadIdx.x;
    const int bh  = blockIdx.x;        // 0..63
    const int ch  = blockIdx.y;        // 0..3
    const int b   = bh >> 4, h = bh & 15;
    const int w   = tid >> 6, lane = tid & 63;
    const int dg  = (lane >> 3) * 8;
    const int eg  = (lane & 7) * 8;
    const size_t base = (size_t)b * TSEQ + (size_t)ch * 512;

    f32x4 acc[8][2] = {};

    for (int ss = 0; ss < 4; ++ss) {
        __syncthreads();
#pragma unroll
        for (int i = 0; i < 4; ++i) {
            const int e = i * 2048 + tid * 8;
            const int t = e >> 6, d = e & 63;
            bf16x8 k8 = *(const bf16x8*)&Kb[(base + ss * 128 + t) * DMODEL + h * 64 + d];
            bf16x8 v8 = *(const bf16x8*)&Vb[(base + ss * 128 + t) * DMODEL + h * 64 + d];
            f32x4 kf0, kf1, vf0, vf1;
#pragma unroll
            for (int j = 0; j < 4; ++j) {
                kf0[j] = (float)k8[j]; kf1[j] = (float)k8[j + 4];
                vf0[j] = (float)v8[j]; vf1[j] = (float)v8[j + 4];
            }
            *(f32x4*)&Ks[t][d]     = kf0;
            *(f32x4*)&Ks[t][d + 4] = kf1;
            *(f32x4*)&Vs[t][d]     = vf0;
            *(f32x4*)&Vs[t][d + 4] = vf1;
        }
        __syncthreads();

#pragma unroll 4
        for (int tt = 0; tt < 32; ++tt) {
            const int t = w * 32 + tt;
            f32x4 kd0 = *(const f32x4*)&Ks[t][dg];
            f32x4 kd1 = *(const f32x4*)&Ks[t][dg + 4];
            f32x4 ve0 = *(const f32x4*)&Vs[t][eg];
            f32x4 ve1 = *(const f32x4*)&Vs[t][eg + 4];
#pragma unroll
            for (int r = 0; r < 8; ++r) {
                const float kd = (r < 4) ? kd0[r] : kd1[r - 4];
                acc[r][0] += ve0 * kd;
                acc[r][1] += ve1 * kd;
            }
        }
    }

    float* o = kvp + ((size_t)(ch * 4 + w) * 64 + bh) * 4096 + (size_t)dg * 64 + eg;
#pragma unroll
    for (int r = 0; r < 8; ++r) {
        *(f32x4*)(o + r * 64)     = acc[r][0];
        *(f32x4*)(o + r * 64 + 4) = acc[r][1];
    }
}

// ---------------------------------------------------------------------------
// reduce 16 partials; kvT[bh][e][d] = scale * sum_c kvp  (e-major for att B)
// ---------------------------------------------------------------------------
__global__ __launch_bounds__(256)
void kv_reduce(const float* __restrict__ kvp, __bf16* __restrict__ kvT)
{
    const int idx = blockIdx.x * 256 + threadIdx.x;   // 0..262143
    const int bh  = idx >> 12;
    const int rem = idx & 4095;
    const int d = rem >> 6, e = rem & 63;
    float s = 0.f;
#pragma unroll
    for (int c = 0; c < 16; ++c) s += kvp[((size_t)c * 64 + bh) * 4096 + rem];
    kvT[(size_t)bh * 4096 + e * 64 + d] = (__bf16)(s * 0.125f);   // 1/sqrt(64)
}

// ---------------------------------------------------------------------------
// att + residual + LayerNorm. 32 rows/block, 256 thr (4 waves, 4 heads each).
// Residual-added x stashed bf16 in LDS (single dec read). f32 out.
// ---------------------------------------------------------------------------
__global__ __launch_bounds__(256)
void att_ln(const __bf16* __restrict__ Q, const __bf16* __restrict__ kvT,
            const float* __restrict__ dec, const float* __restrict__ gamma,
            const float* __restrict__ beta, float* __restrict__ out)
{
    __shared__ __align__(16) __bf16 att_s[32][1032];   // +8 pad

    const int tid  = threadIdx.x;
    const int lane = tid & 63;
    const int w    = tid >> 6;
    const int l4   = lane & 15, g4 = lane >> 4;
    const int t0   = blockIdx.x * 32;
    const int b    = t0 >> 11;

#pragma unroll
    for (int i = 0; i < 4; ++i) {
        const int h = w * 4 + i;
        f32x4 acc[2][4] = {};
#pragma unroll
        for (int kk = 0; kk < 2; ++kk) {
            bf16x8 a0 = *(const bf16x8*)&Q[(size_t)(t0 + l4) * DMODEL + h * 64 + kk * 32 + g4 * 8];
            bf16x8 a1 = *(const bf16x8*)&Q[(size_t)(t0 + 16 + l4) * DMODEL + h * 64 + kk * 32 + g4 * 8];
#pragma unroll
            for (int n = 0; n < 4; ++n) {
                bf16x8 bb = *(const bf16x8*)&kvT[(size_t)(b * 16 + h) * 4096 + (n * 16 + l4) * 64 + kk * 32 + g4 * 8];
                acc[0][n] = __builtin_amdgcn_mfma_f32_16x16x32_bf16(a0, bb, acc[0][n], 0, 0, 0);
                acc[1][n] = __builtin_amdgcn_mfma_f32_16x16x32_bf16(a1, bb, acc[1][n], 0, 0, 0);
            }
        }
#pragma unroll
        for (int m = 0; m < 2; ++m)
#pragma unroll
            for (int n = 0; n < 4; ++n)
#pragma unroll
                for (int j = 0; j < 4; ++j)
                    att_s[m * 16 + g4 * 4 + j][h * 64 + n * 16 + l4] = (__bf16)acc[m][n][j];
    }
    __syncthreads();

    // LN: 8 threads per row
    const int r = tid >> 3, seg = tid & 7;
    const size_t grow = (size_t)t0 + r;
    float sum = 0.f, ss2 = 0.f;
#pragma unroll
    for (int i = 0; i < 16; ++i) {
        const int c0 = seg * 8 + i * 64;
        bf16x8 av = *(const bf16x8*)&att_s[r][c0];
        f32x4 d0 = *(const f32x4*)&dec[grow * DMODEL + c0];
        f32x4 d1 = *(const f32x4*)&dec[grow * DMODEL + c0 + 4];
        bf16x8 xs;
#pragma unroll
        for (int j = 0; j < 4; ++j) {
            const float x0 = (float)av[j] + d0[j];
            const float x1 = (float)av[j + 4] + d1[j];
            sum += x0 + x1; ss2 += x0 * x0 + x1 * x1;
            xs[j] = (__bf16)x0; xs[j + 4] = (__bf16)x1;
        }
        *(bf16x8*)&att_s[r][c0] = xs;
    }
    sum += __shfl_xor(sum, 1); ss2 += __shfl_xor(ss2, 1);
    sum += __shfl_xor(sum, 2); ss2 += __shfl_xor(ss2, 2);
    sum += __shfl_xor(sum, 4); ss2 += __shfl_xor(ss2, 4);
    const float mu   = sum * (1.f / 1024.f);
    const float var  = ss2 * (1.f / 1024.f) - mu * mu;
    const float rstd = rsqrtf(var + 1e-5f);

#pragma unroll
    for (int i = 0; i < 16; ++i) {
        const int c0 = seg * 8 + i * 64;
        bf16x8 xv = *(const bf16x8*)&att_s[r][c0];
        f32x4 g0 = *(const f32x4*)&gamma[c0];
        f32x4 g1 = *(const f32x4*)&gamma[c0 + 4];
        f32x4 b0 = *(const f32x4*)&beta[c0];
        f32x4 b1 = *(const f32x4*)&beta[c0 + 4];
        f32x4 y0, y1;
#pragma unroll
        for (int j = 0; j < 4; ++j) {
            y0[j] = ((float)xv[j]     - mu) * rstd * g0[j] + b0[j];
            y1[j] = ((float)xv[j + 4] - mu) * rstd * g1[j] + b1[j];
        }
        *(f32x4*)&out[grow * DMODEL + c0]     = y0;
        *(f32x4*)&out[grow * DMODEL + c0 + 4] = y1;
    }
}

// ---------------------------------------------------------------------------
extern "C" void kernel_launch(void* const* d_in, const int* in_sizes, int n_in,
                              void* d_out, int out_size, void* d_ws, size_t ws_size,
                              hipStream_t stream)
{
    const float* enc   = (const float*)d_in[0];
    const float* dec   = (const float*)d_in[1];
    const float* Wq    = (const float*)d_in[2];
    const float* bq    = (const float*)d_in[3];
    const float* Wk    = (const float*)d_in[4];
    const float* bk    = (const float*)d_in[5];
    const float* Wv    = (const float*)d_in[6];
    const float* bv    = (const float*)d_in[7];
    const float* gamma = (const float*)d_in[8];
    const float* beta  = (const float*)d_in[9];

    char* ws = (char*)d_ws;
    __bf16* Qb  = (__bf16*)(ws + QB_OFF);
    __bf16* Kb  = (__bf16*)(ws + KB_OFF);
    __bf16* Vb  = (__bf16*)(ws + VB_OFF);
    float*  kvp = (float*) (ws + KVP_OFF);
    __bf16* WB  = (__bf16*)(ws + WB_OFF);
    __bf16* kvT = (__bf16*)(ws + KVT_OFF);

    conv_w<<<1536, 256, 0, stream>>>(Wq, Wk, Wv, WB);
    qkv_gemm<<<dim3(24, 64), 256, 0, stream>>>(dec, enc, WB, bq, bk, bv, Qb, Kb, Vb);
    kv_mm<<<dim3(64, 4), 256, 0, stream>>>(Kb, Vb, kvp);
    kv_reduce<<<1024, 256, 0, stream>>>(kvp, kvT);
    att_ln<<<256, 256, 0, stream>>>(Qb, kvT, dec, gamma, beta, (float*)d_out);
}

// Round 5
// 143.263 us; speedup vs baseline: 1.2529x; 1.0431x over previous
//
#include <hip/hip_runtime.h>
#include <hip/hip_bf16.h>
#include <stdint.h>
#include <stddef.h>

typedef __attribute__((ext_vector_type(8))) __bf16 bf16x8;
typedef __attribute__((ext_vector_type(4))) float f32x4;

#define DMODEL 1024
#define HEADS  16
#define BATCH  4
#define TSEQ   2048
#define MROWS  (BATCH * TSEQ)   // 8192

#define MiB (size_t)1048576
#define QB_OFF   ((size_t)0)          // 16 MiB bf16
#define KB_OFF   (16 * MiB)           // 16 MiB bf16
#define VB_OFF   (32 * MiB)           // 16 MiB bf16
#define KVP_OFF  (48 * MiB)           // 16 MiB f32 partials
#define WB_OFF   (64 * MiB)           // 6 MiB bf16 (Wq,Wk,Wv)
#define KVT_OFF  (70 * MiB)           // 512 KiB bf16

// ---------------------------------------------------------------------------
// convert the 3 weight matrices f32 -> bf16 (one launch, 18 MB traffic)
// ---------------------------------------------------------------------------
__global__ __launch_bounds__(256)
void conv_w(const float* __restrict__ Wq, const float* __restrict__ Wk,
            const float* __restrict__ Wv, __bf16* __restrict__ WB)
{
    const int bid = blockIdx.x;            // 0..1535
    const int sel = bid >> 9, blk = bid & 511;
    const float* src = (sel == 0) ? Wq : (sel == 1) ? Wk : Wv;
    const int i = blk * 2048 + threadIdx.x * 8;
    f32x4 a = *(const f32x4*)(src + i);
    f32x4 b = *(const f32x4*)(src + i + 4);
    bf16x8 o;
#pragma unroll
    for (int j = 0; j < 4; ++j) { o[j] = (__bf16)a[j]; o[j + 4] = (__bf16)b[j]; }
    *(bf16x8*)&WB[(size_t)sel * (DMODEL * DMODEL) + i] = o;
}

// ---------------------------------------------------------------------------
// Fused QKV GEMM: C = A[M,K](f32, inline-cvt) @ W[N,K]^T(bf16) + bias(f32)
// m97 structure: 128x128 tile, BK=32, 4 waves, dbuf LDS.
// XCD-slab decode (T1): flat grid 1536; consecutive blockIdx round-robin
// across the 8 XCDs, so slab = bid&7 pins all 24 (sel,bn) tiles of 8
// consecutive bm values to ONE XCD -> each A panel is fetched by exactly
// one XCD's L2 (A traffic 64 MB total instead of ~8x that).
// ---------------------------------------------------------------------------
__global__ __launch_bounds__(256)
void qkv_gemm(const float* __restrict__ dec, const float* __restrict__ enc,
              const __bf16* __restrict__ WB,
              const float* __restrict__ bq, const float* __restrict__ bk,
              const float* __restrict__ bv,
              __bf16* __restrict__ Qb, __bf16* __restrict__ Kb,
              __bf16* __restrict__ Vb)
{
    __shared__ __align__(16) __bf16 sA[2][128 * 32];
    __shared__ __align__(16) __bf16 sB[2][128 * 32];

    const int tid  = threadIdx.x;
    const int lane = tid & 63;
    const int wv   = tid >> 6;
    const int wm   = wv >> 1;
    const int wn   = wv & 1;

    const int bid  = blockIdx.x;       // 0..1535
    const int slab = bid & 7;          // XCD id (round-robin dispatch)
    const int idx  = bid >> 3;         // 0..191 within slab
    const int bm   = slab * 8 + idx / 24;   // 0..63
    const int bx   = idx % 24;         // 0..23
    const int sel  = bx >> 3;          // 0=Q 1=K 2=V
    const int bn   = bx & 7;

    const float*  A    = (sel == 0) ? dec : enc;
    const __bf16* W    = WB + (size_t)sel * (DMODEL * DMODEL);
    const float*  bias = (sel == 0) ? bq : (sel == 1) ? bk : bv;
    __bf16*       C    = (sel == 0) ? Qb : (sel == 1) ? Kb : Vb;

    const int l4 = lane & 15;
    const int g4 = lane >> 4;
    const int NT = DMODEL / 32;        // 32 K-steps

    // staging maps (tile 128x32): bf16 idx = p*2048 + tid*8 -> row=idx>>5, k=idx&31
    const int r0 = tid >> 2;           // pass0 row (pass1: +64)
    const int k0 = (tid & 3) * 8;      // k within 32

    auto loadA = [&](int kt, f32x4 a[4]) {
#pragma unroll
        for (int p = 0; p < 2; ++p) {
            const float* src = A + (size_t)(bm * 128 + p * 64 + r0) * DMODEL + kt * 32 + k0;
            a[2 * p]     = *(const f32x4*)src;
            a[2 * p + 1] = *(const f32x4*)(src + 4);
        }
    };
    auto writeA = [&](int buf, f32x4 a[4]) {
#pragma unroll
        for (int p = 0; p < 2; ++p) {
            bf16x8 o;
#pragma unroll
            for (int j = 0; j < 4; ++j) {
                o[j]     = (__bf16)a[2 * p][j];
                o[j + 4] = (__bf16)a[2 * p + 1][j];
            }
            *(bf16x8*)&sA[buf][p * 2048 + tid * 8] = o;
        }
    };
    auto stageB = [&](int buf, int kt) {
#pragma unroll
        for (int p = 0; p < 2; ++p) {
            const int idx2 = p * 2048 + tid * 8;
            __builtin_amdgcn_global_load_lds(
                (const __attribute__((address_space(1))) void*)
                    (W + (size_t)(bn * 128 + p * 64 + r0) * DMODEL + kt * 32 + k0),
                (__attribute__((address_space(3))) void*)(&sB[buf][idx2]), 16, 0, 0);
        }
    };

    f32x4 acc[4][4] = {};

    {
        f32x4 a0[4];
        loadA(0, a0);
        stageB(0, 0);
        writeA(0, a0);
    }
    __syncthreads();

    int buf = 0;
    for (int kt = 0; kt < NT; ++kt) {
        f32x4 an[4];
        const bool more = (kt + 1 < NT);
        if (more) { loadA(kt + 1, an); stageB(buf ^ 1, kt + 1); }

        bf16x8 af[4], bfr[4];
#pragma unroll
        for (int m = 0; m < 4; ++m)
            af[m] = *(const bf16x8*)&sA[buf][(wm * 64 + m * 16 + l4) * 32 + g4 * 8];
#pragma unroll
        for (int n = 0; n < 4; ++n)
            bfr[n] = *(const bf16x8*)&sB[buf][(wn * 64 + n * 16 + l4) * 32 + g4 * 8];

#pragma unroll
        for (int m = 0; m < 4; ++m)
#pragma unroll
            for (int n = 0; n < 4; ++n)
                acc[m][n] = __builtin_amdgcn_mfma_f32_16x16x32_bf16(af[m], bfr[n], acc[m][n], 0, 0, 0);

        if (more) writeA(buf ^ 1, an);
        __syncthreads();
        buf ^= 1;
    }

    // epilogue: C/D layout col = lane&15, row = (lane>>4)*4 + j
    const int crow0 = bm * 128 + wm * 64 + g4 * 4;
    const int ccol0 = bn * 128 + wn * 64 + l4;
#pragma unroll
    for (int n = 0; n < 4; ++n) {
        const int cc = ccol0 + n * 16;
        const float bv2 = bias[cc];
#pragma unroll
        for (int m = 0; m < 4; ++m) {
            const int rr = crow0 + m * 16;
#pragma unroll
            for (int j = 0; j < 4; ++j)
                C[(size_t)(rr + j) * DMODEL + cc] = (__bf16)(acc[m][n][j] + bv2);
        }
    }
}

// ---------------------------------------------------------------------------
// kv partials, register-tiled: block = (bh, chunk of 512 t), 4 waves.
// Wave w handles t-slice w*32..+32 of each 128-row substage; lane owns an
// 8x8 (d,e) tile -> 64 FMA per 32 B LDS read (compute-bound).
// ---------------------------------------------------------------------------
__global__ __launch_bounds__(256)
void kv_mm(const __bf16* __restrict__ Kb, const __bf16* __restrict__ Vb,
           float* __restrict__ kvp)
{
    __shared__ __align__(16) float Ks[128][64];
    __shared__ __align__(16) float Vs[128][64];

    const int tid = threadIdx.x;
    const int bh  = blockIdx.x;        // 0..63
    const int ch  = blockIdx.y;        // 0..3
    const int b   = bh >> 4, h = bh & 15;
    const int w   = tid >> 6, lane = tid & 63;
    const int dg  = (lane >> 3) * 8;
    const int eg  = (lane & 7) * 8;
    const size_t base = (size_t)b * TSEQ + (size_t)ch * 512;

    f32x4 acc[8][2] = {};

    for (int ss = 0; ss < 4; ++ss) {
        __syncthreads();
#pragma unroll
        for (int i = 0; i < 4; ++i) {
            const int e = i * 2048 + tid * 8;
            const int t = e >> 6, d = e & 63;
            bf16x8 k8 = *(const bf16x8*)&Kb[(base + ss * 128 + t) * DMODEL + h * 64 + d];
            bf16x8 v8 = *(const bf16x8*)&Vb[(base + ss * 128 + t) * DMODEL + h * 64 + d];
            f32x4 kf0, kf1, vf0, vf1;
#pragma unroll
            for (int j = 0; j < 4; ++j) {
                kf0[j] = (float)k8[j]; kf1[j] = (float)k8[j + 4];
                vf0[j] = (float)v8[j]; vf1[j] = (float)v8[j + 4];
            }
            *(f32x4*)&Ks[t][d]     = kf0;
            *(f32x4*)&Ks[t][d + 4] = kf1;
            *(f32x4*)&Vs[t][d]     = vf0;
            *(f32x4*)&Vs[t][d + 4] = vf1;
        }
        __syncthreads();

#pragma unroll 4
        for (int tt = 0; tt < 32; ++tt) {
            const int t = w * 32 + tt;
            f32x4 kd0 = *(const f32x4*)&Ks[t][dg];
            f32x4 kd1 = *(const f32x4*)&Ks[t][dg + 4];
            f32x4 ve0 = *(const f32x4*)&Vs[t][eg];
            f32x4 ve1 = *(const f32x4*)&Vs[t][eg + 4];
#pragma unroll
            for (int r = 0; r < 8; ++r) {
                const float kd = (r < 4) ? kd0[r] : kd1[r - 4];
                acc[r][0] += ve0 * kd;
                acc[r][1] += ve1 * kd;
            }
        }
    }

    float* o = kvp + ((size_t)(ch * 4 + w) * 64 + bh) * 4096 + (size_t)dg * 64 + eg;
#pragma unroll
    for (int r = 0; r < 8; ++r) {
        *(f32x4*)(o + r * 64)     = acc[r][0];
        *(f32x4*)(o + r * 64 + 4) = acc[r][1];
    }
}

// ---------------------------------------------------------------------------
// reduce 16 partials; kvT[bh][e][d] = scale * sum_c kvp  (e-major for att B)
// ---------------------------------------------------------------------------
__global__ __launch_bounds__(256)
void kv_reduce(const float* __restrict__ kvp, __bf16* __restrict__ kvT)
{
    const int idx = blockIdx.x * 256 + threadIdx.x;   // 0..262143
    const int bh  = idx >> 12;
    const int rem = idx & 4095;
    const int d = rem >> 6, e = rem & 63;
    float s = 0.f;
#pragma unroll
    for (int c = 0; c < 16; ++c) s += kvp[((size_t)c * 64 + bh) * 4096 + rem];
    kvT[(size_t)bh * 4096 + e * 64 + d] = (__bf16)(s * 0.125f);   // 1/sqrt(64)
}

// ---------------------------------------------------------------------------
// att + residual + LayerNorm. 32 rows/block, 256 thr (4 waves, 4 heads each).
// Residual-added x stashed bf16 in LDS (single dec read). f32 out.
// ---------------------------------------------------------------------------
__global__ __launch_bounds__(256)
void att_ln(const __bf16* __restrict__ Q, const __bf16* __restrict__ kvT,
            const float* __restrict__ dec, const float* __restrict__ gamma,
            const float* __restrict__ beta, float* __restrict__ out)
{
    __shared__ __align__(16) __bf16 att_s[32][1032];   // +8 pad

    const int tid  = threadIdx.x;
    const int lane = tid & 63;
    const int w    = tid >> 6;
    const int l4   = lane & 15, g4 = lane >> 4;
    const int t0   = blockIdx.x * 32;
    const int b    = t0 >> 11;

#pragma unroll
    for (int i = 0; i < 4; ++i) {
        const int h = w * 4 + i;
        f32x4 acc[2][4] = {};
#pragma unroll
        for (int kk = 0; kk < 2; ++kk) {
            bf16x8 a0 = *(const bf16x8*)&Q[(size_t)(t0 + l4) * DMODEL + h * 64 + kk * 32 + g4 * 8];
            bf16x8 a1 = *(const bf16x8*)&Q[(size_t)(t0 + 16 + l4) * DMODEL + h * 64 + kk * 32 + g4 * 8];
#pragma unroll
            for (int n = 0; n < 4; ++n) {
                bf16x8 bb = *(const bf16x8*)&kvT[(size_t)(b * 16 + h) * 4096 + (n * 16 + l4) * 64 + kk * 32 + g4 * 8];
                acc[0][n] = __builtin_amdgcn_mfma_f32_16x16x32_bf16(a0, bb, acc[0][n], 0, 0, 0);
                acc[1][n] = __builtin_amdgcn_mfma_f32_16x16x32_bf16(a1, bb, acc[1][n], 0, 0, 0);
            }
        }
#pragma unroll
        for (int m = 0; m < 2; ++m)
#pragma unroll
            for (int n = 0; n < 4; ++n)
#pragma unroll
                for (int j = 0; j < 4; ++j)
                    att_s[m * 16 + g4 * 4 + j][h * 64 + n * 16 + l4] = (__bf16)acc[m][n][j];
    }
    __syncthreads();

    // LN: 8 threads per row
    const int r = tid >> 3, seg = tid & 7;
    const size_t grow = (size_t)t0 + r;
    float sum = 0.f, ss2 = 0.f;
#pragma unroll
    for (int i = 0; i < 16; ++i) {
        const int c0 = seg * 8 + i * 64;
        bf16x8 av = *(const bf16x8*)&att_s[r][c0];
        f32x4 d0 = *(const f32x4*)&dec[grow * DMODEL + c0];
        f32x4 d1 = *(const f32x4*)&dec[grow * DMODEL + c0 + 4];
        bf16x8 xs;
#pragma unroll
        for (int j = 0; j < 4; ++j) {
            const float x0 = (float)av[j] + d0[j];
            const float x1 = (float)av[j + 4] + d1[j];
            sum += x0 + x1; ss2 += x0 * x0 + x1 * x1;
            xs[j] = (__bf16)x0; xs[j + 4] = (__bf16)x1;
        }
        *(bf16x8*)&att_s[r][c0] = xs;
    }
    sum += __shfl_xor(sum, 1); ss2 += __shfl_xor(ss2, 1);
    sum += __shfl_xor(sum, 2); ss2 += __shfl_xor(ss2, 2);
    sum += __shfl_xor(sum, 4); ss2 += __shfl_xor(ss2, 4);
    const float mu   = sum * (1.f / 1024.f);
    const float var  = ss2 * (1.f / 1024.f) - mu * mu;
    const float rstd = rsqrtf(var + 1e-5f);

#pragma unroll
    for (int i = 0; i < 16; ++i) {
        const int c0 = seg * 8 + i * 64;
        bf16x8 xv = *(const bf16x8*)&att_s[r][c0];
        f32x4 g0 = *(const f32x4*)&gamma[c0];
        f32x4 g1 = *(const f32x4*)&gamma[c0 + 4];
        f32x4 b0 = *(const f32x4*)&beta[c0];
        f32x4 b1 = *(const f32x4*)&beta[c0 + 4];
        f32x4 y0, y1;
#pragma unroll
        for (int j = 0; j < 4; ++j) {
            y0[j] = ((float)xv[j]     - mu) * rstd * g0[j] + b0[j];
            y1[j] = ((float)xv[j + 4] - mu) * rstd * g1[j] + b1[j];
        }
        *(f32x4*)&out[grow * DMODEL + c0]     = y0;
        *(f32x4*)&out[grow * DMODEL + c0 + 4] = y1;
    }
}

// ---------------------------------------------------------------------------
extern "C" void kernel_launch(void* const* d_in, const int* in_sizes, int n_in,
                              void* d_out, int out_size, void* d_ws, size_t ws_size,
                              hipStream_t stream)
{
    const float* enc   = (const float*)d_in[0];
    const float* dec   = (const float*)d_in[1];
    const float* Wq    = (const float*)d_in[2];
    const float* bq    = (const float*)d_in[3];
    const float* Wk    = (const float*)d_in[4];
    const float* bk    = (const float*)d_in[5];
    const float* Wv    = (const float*)d_in[6];
    const float* bv    = (const float*)d_in[7];
    const float* gamma = (const float*)d_in[8];
    const float* beta  = (const float*)d_in[9];

    char* ws = (char*)d_ws;
    __bf16* Qb  = (__bf16*)(ws + QB_OFF);
    __bf16* Kb  = (__bf16*)(ws + KB_OFF);
    __bf16* Vb  = (__bf16*)(ws + VB_OFF);
    float*  kvp = (float*) (ws + KVP_OFF);
    __bf16* WB  = (__bf16*)(ws + WB_OFF);
    __bf16* kvT = (__bf16*)(ws + KVT_OFF);

    conv_w<<<1536, 256, 0, stream>>>(Wq, Wk, Wv, WB);
    qkv_gemm<<<1536, 256, 0, stream>>>(dec, enc, WB, bq, bk, bv, Qb, Kb, Vb);
    kv_mm<<<dim3(64, 4), 256, 0, stream>>>(Kb, Vb, kvp);
    kv_reduce<<<1024, 256, 0, stream>>>(kvp, kvT);
    att_ln<<<256, 256, 0, stream>>>(Qb, kvT, dec, gamma, beta, (float*)d_out);
}